// Round 9
// baseline (6449.469 us; speedup 1.0000x reference)
//
#include <hip/hip_runtime.h>
#include <stdint.h>

#define BB 64
#define TT 512
#define EE 512
#define HH 1024
#define GG 4096

#define NSG 64          // WGs per stage
#define XP0_SLOTS 8
#define RS 8            // h0/h1/xp1 ring slots

typedef short v8b __attribute__((ext_vector_type(8)));
typedef float v4f __attribute__((ext_vector_type(4)));
typedef unsigned short u16;
typedef unsigned int u32;
typedef unsigned long long u64;

__device__ __forceinline__ u16 f2bf(float f) {
  union { float f; u32 i; } v; v.f = f;
  u32 u = v.i;
  return (u16)((u + 0x7FFFu + ((u >> 16) & 1u)) >> 16);
}
__device__ __forceinline__ float sigm(float x) { return 1.0f / (1.0f + __expf(-x)); }
// fast tanh: 1 - 2/(e^{2x}+1); monotone-safe for all x (no inf/inf)
__device__ __forceinline__ float ftanh(float x) {
  float e = __expf(2.0f * x);
  return 1.0f - 2.0f / (e + 1.0f);
}

// ---- 16B MALL-coherent loads: ONE dwordx4 (sc0 sc1 = system scope, bypasses
// L1/L2 like the agent-scope atomics) -> sector-exact, half the request count
// of 2x8B atomic loads. Results are INVALID until the explicit vmcnt(0).
__device__ __forceinline__ v8b ld16cc(const u16* p) {
  v8b r;
  asm volatile("global_load_dwordx4 %0, %1, off sc0 sc1" : "=v"(r) : "v"(p));
  return r;
}
__device__ __forceinline__ v4f ldf16cc(const float* p) {
  v4f r;
  asm volatile("global_load_dwordx4 %0, %1, off sc0 sc1" : "=v"(r) : "v"(p));
  return r;
}
__device__ __forceinline__ void wait_loads() {
  asm volatile("s_waitcnt vmcnt(0)" ::: "memory");
  __builtin_amdgcn_sched_barrier(0);   // rule #18: stop MFMA hoisting past the wait
}

// ---- MALL-direct stores (agent scope) ----
__device__ __forceinline__ void stg16_f(float* p, v4f v) {
  union { v4f f; u64 q[2]; } u; u.f = v;
  __hip_atomic_store((u64*)p,     u.q[0], __ATOMIC_RELAXED, __HIP_MEMORY_SCOPE_AGENT);
  __hip_atomic_store((u64*)p + 1, u.q[1], __ATOMIC_RELAXED, __HIP_MEMORY_SCOPE_AGENT);
}
__device__ __forceinline__ void stg2_h(u16* p, u16 v) {
  __hip_atomic_store(p, v, __ATOMIC_RELAXED, __HIP_MEMORY_SCOPE_AGENT);
}
__device__ __forceinline__ void stg4_f(float* p, float v) {
  __hip_atomic_store(p, v, __ATOMIC_RELAXED, __HIP_MEMORY_SCOPE_AGENT);
}
__device__ __forceinline__ void drain_stores() {
  asm volatile("s_waitcnt vmcnt(0)" ::: "memory");
}

// ---------------- flag helpers (R3-exact: serial && spin, measured best) ----------------
__device__ __forceinline__ u32 ldflag(const u32* p) {
  return __hip_atomic_load(p, __ATOMIC_RELAXED, __HIP_MEMORY_SCOPE_AGENT);
}
__device__ __forceinline__ void spin3(const u32* p0, u32 v0,
                                      const u32* p1, u32 v1,
                                      const u32* p2, u32 v2) {
  for (;;) {
    bool ok = (ldflag(p0) >= v0) && (ldflag(p1) >= v1) && (ldflag(p2) >= v2);
    if (__all((int)ok)) break;
    __builtin_amdgcn_s_sleep(1);
  }
}
__device__ __forceinline__ void postw(u32* f, u32 v, int lane) {
  if (lane == 0)
    __hip_atomic_store(f, v, __ATOMIC_RELAXED, __HIP_MEMORY_SCOPE_AGENT);
}

// ---------------- prep: gather embeddings (fp32->bf16), zero flags + h rings, lens ----------
__global__ void prep_kernel(const int* __restrict__ x, const float* __restrict__ emb,
                            u16* __restrict__ e16, u16* __restrict__ h0r, u16* __restrict__ h1r,
                            int* __restrict__ lens, u32* flags, int flag_u32s) {
  long stride = (long)gridDim.x * blockDim.x;
  long gid = (long)blockIdx.x * blockDim.x + threadIdx.x;
  const long totalE = (long)BB * TT * EE;
  for (long i = gid; i < totalE; i += stride) {
    int d = (int)(i % EE);
    long bt = i / EE;
    int tok = x[bt];
    e16[i] = f2bf(emb[(long)tok * EE + d]);
  }
  for (long i = gid; i < (long)flag_u32s; i += stride) flags[i] = 0u;
  const long ringN = (long)RS * BB * HH;
  for (long i = gid; i < ringN; i += stride) { h0r[i] = 0; h1r[i] = 0; }
  int gwave = (int)(gid >> 6);
  int lane = (int)(gid & 63);
  if (gwave < BB) {
    int cnt = 0;
    for (int t2 = lane; t2 < TT; t2 += 64) cnt += (x[gwave * TT + t2] == 0) ? 1 : 0;
    for (int off = 32; off; off >>= 1) cnt += __shfl_down(cnt, off, 64);
    if (lane == 0) lens[gwave] = TT - cnt;
  }
}

extern __shared__ short Wlds[];  // 128 KB weights only (LDS h-staging removed)

// one 32-wide K-block: 4 ds_read_b128 (4 n-tiles of 16 rows) + 4 MFMA
#define KQUAD(FR, PK) \
  { const short* wb = &Wlds[(((PK) * 4 + q) * 64 + m16) * 8]; \
    v8b w0 = *(const v8b*)(wb); \
    v8b w1 = *(const v8b*)(wb + 128); \
    v8b w2 = *(const v8b*)(wb + 256); \
    v8b w3 = *(const v8b*)(wb + 384); \
    a0 = __builtin_amdgcn_mfma_f32_16x16x32_bf16(FR, w0, a0, 0, 0, 0); \
    a1 = __builtin_amdgcn_mfma_f32_16x16x32_bf16(FR, w1, a1, 0, 0, 0); \
    a2 = __builtin_amdgcn_mfma_f32_16x16x32_bf16(FR, w2, a2, 0, 0, 0); \
    a3 = __builtin_amdgcn_mfma_f32_16x16x32_bf16(FR, w3, a3, 0, 0, 0); }

// K=1024 recurrent GEMM for one wave's 16-batch group.
// Direct MFMA A-fragment MALL reads: lane m16 = batch row, 16B/lane, 4 q-lanes
// cover one 64B sector -> sector-exact, no LDS staging, no ds ping-pong.
// All 32 loads issued up front (bulk, one amortized RT), then 32 KQUADs.
__device__ __forceinline__ void kh_direct(const u16* hbase /* slot + group base */,
                                          int q, int m16,
                                          v4f& a0, v4f& a1, v4f& a2, v4f& a3) {
  const u16* hp = hbase + (long)m16 * HH + q * 8;
  v8b H[32];
#pragma unroll
  for (int kb = 0; kb < 32; ++kb) H[kb] = ld16cc(hp + kb * 32);
  wait_loads();
#pragma unroll
  for (int kb = 0; kb < 32; ++kb) KQUAD(H[kb], kb);
}

// ---------------- persistent pipeline kernel: 4 stages x 64 WGs, 1 WG/CU ----------------
// Each wave = independent 16-batch pipeline (no __syncthreads in the t-loop).
__global__ __launch_bounds__(256, 1) void lstm_persist(
    const u16* __restrict__ e16,
    const float* __restrict__ Wih0, const float* __restrict__ Whh0, const float* __restrict__ b0,
    const float* __restrict__ Wih1, const float* __restrict__ Whh1, const float* __restrict__ b1,
    const int* __restrict__ lens,
    float* __restrict__ xp0, float* __restrict__ xp1,
    u16* __restrict__ h0r, u16* __restrict__ h1r,
    float* __restrict__ lasth,
    u32* fA0, u32* fL0, u32* fA1, u32* fL1) {
  const int wg = blockIdx.x;
  const int tid = threadIdx.x;
  const int g = tid >> 6;            // wave = batch group (16 batches)
  const int lane = tid & 63;
  const int m16 = lane & 15;
  const int q = lane >> 4;
  const int bq = g * 16 + q * 4;     // C-tile batch base
  const int stage = wg >> 6;
  const int sid = wg & 63;

  if (stage == 0) {
    // ===== A0: xp0[t] = W_ih0 @ e_t + b0 (rows sid*64..+63, K=512) =====
    const int rbase = sid * 64;
    for (int c2 = tid; c2 < 64 * 64; c2 += 256) {
      int r = c2 >> 6, kb = c2 & 63;
      const float* src = Wih0 + (long)(rbase + r) * EE + kb * 8;
      v8b w;
#pragma unroll
      for (int j = 0; j < 8; ++j) w[j] = (short)f2bf(src[j]);
      *(v8b*)&Wlds[(kb * 64 + r) * 8] = w;
    }
    __syncthreads();
    float bias[4];
#pragma unroll
    for (int nt = 0; nt < 4; ++nt) bias[nt] = b0[rbase + nt * 16 + m16];
    const u32* cf = fL0 + g * 64 + (sid & 15) * 4 + (lane & 3);  // L0 consumers of our rows
    u32* myf = fA0 + g * 64 + sid;
    for (int t = 0; t < TT; ++t) {
      if (t >= XP0_SLOTS) spin3(cf, (u32)(t - XP0_SLOTS + 1), cf, 0u, cf, 0u);
      v4f a0 = {0,0,0,0}, a1 = {0,0,0,0}, a2 = {0,0,0,0}, a3 = {0,0,0,0};
      const u16* ap = e16 + (long)(g * 16 + m16) * (TT * EE) + (long)t * EE + q * 8;
#pragma unroll
      for (int kb = 0; kb < 16; ++kb) {
        v8b fr = *(const v8b*)(ap + kb * 32);  // plain cached load (e16 static)
        KQUAD(fr, kb);
      }
      float* xpS = xp0 + (long)(t & (XP0_SLOTS - 1)) * (GG * BB);
      stg16_f(&xpS[(long)(rbase + 0 * 16 + m16) * BB + bq], a0 + bias[0]);
      stg16_f(&xpS[(long)(rbase + 1 * 16 + m16) * BB + bq], a1 + bias[1]);
      stg16_f(&xpS[(long)(rbase + 2 * 16 + m16) * BB + bq], a2 + bias[2]);
      stg16_f(&xpS[(long)(rbase + 3 * 16 + m16) * BB + bq], a3 + bias[3]);
      drain_stores();
      postw(myf, (u32)(t + 1), lane);
    }
  } else if (stage == 1) {
    // ===== L0: gates = xp0 + W_hh0 @ h0[t-1]; 16 units, lane-local cell =====
    const int ubase = sid * 16;
    for (int c2 = tid; c2 < 64 * 128; c2 += 256) {
      int r = c2 >> 7, kb = c2 & 127;
      int grow = (r >> 4) * HH + ubase + (r & 15);  // rows: [i 0..15 | f | g | o]
      const float* src = Whh0 + (long)grow * HH + kb * 8;
      v8b w;
#pragma unroll
      for (int j = 0; j < 8; ++j) w[j] = (short)f2bf(src[j]);
      *(v8b*)&Wlds[(kb * 64 + r) * 8] = w;
    }
    __syncthreads();
    float cst[4] = {0.f, 0.f, 0.f, 0.f};
    const u32* fa = fA0 + g * 64 + ((lane & 3) << 4) + (sid >> 2);  // 4 xp producers
    const u32* fp = fL0 + g * 64 + lane;                            // 64 h peers
    const u32* fr_ = fA1 + g * 64 + lane;                           // h0 ring consumers
    u32* myf = fL0 + g * 64 + sid;
    for (int t = 0; t < TT; ++t) {
      spin3(fa, (u32)(t + 1), fp, (u32)t, fr_, (t >= RS) ? (u32)(t - RS + 1) : 0u);
      const float* xpS = xp0 + (long)(t & (XP0_SLOTS - 1)) * (GG * BB);
      v4f xq0 = ldf16cc(&xpS[(long)(0 * HH + ubase + m16) * BB + bq]);
      v4f xq1 = ldf16cc(&xpS[(long)(1 * HH + ubase + m16) * BB + bq]);
      v4f xq2 = ldf16cc(&xpS[(long)(2 * HH + ubase + m16) * BB + bq]);
      v4f xq3 = ldf16cc(&xpS[(long)(3 * HH + ubase + m16) * BB + bq]);
      v4f a0 = {0,0,0,0}, a1 = {0,0,0,0}, a2 = {0,0,0,0}, a3 = {0,0,0,0};
      const u16* hb = h0r + ((t + RS - 1) & (RS - 1)) * (BB * HH) + (long)(g * 16) * HH;
      kh_direct(hb, q, m16, a0, a1, a2, a3);   // vmcnt(0) inside also covers xq loads
      a0 += xq0; a1 += xq1; a2 += xq2; a3 += xq3;   // i, f, g, o
      u16* hw = h0r + (t & (RS - 1)) * (BB * HH);
#pragma unroll
      for (int r = 0; r < 4; ++r) {
        float cn = sigm(a1[r]) * cst[r] + sigm(a0[r]) * ftanh(a2[r]);
        cst[r] = cn;
        float hv = sigm(a3[r]) * ftanh(cn);
        stg2_h(&hw[(bq + r) * HH + ubase + m16], f2bf(hv));
      }
      drain_stores();
      postw(myf, (u32)(t + 1), lane);
    }
  } else if (stage == 2) {
    // ===== A1: xp1[t] = W_ih1 @ h0[t] + b1 (rows sid*64..+63, K=1024) =====
    const int rbase = sid * 64;
    for (int c2 = tid; c2 < 64 * 128; c2 += 256) {
      int r = c2 >> 7, kb = c2 & 127;
      const float* src = Wih1 + (long)(rbase + r) * HH + kb * 8;
      v8b w;
#pragma unroll
      for (int j = 0; j < 8; ++j) w[j] = (short)f2bf(src[j]);
      *(v8b*)&Wlds[(kb * 64 + r) * 8] = w;
    }
    __syncthreads();
    float bias[4];
#pragma unroll
    for (int nt = 0; nt < 4; ++nt) bias[nt] = b1[rbase + nt * 16 + m16];
    const u32* fp = fL0 + g * 64 + lane;                           // h0 producers
    const u32* fc = fL1 + g * 64 + (sid & 15) * 4 + (lane & 3);   // xp1 ring consumers
    u32* myf = fA1 + g * 64 + sid;
    for (int t = 0; t < TT; ++t) {
      spin3(fp, (u32)(t + 1), fc, (t >= RS) ? (u32)(t - RS + 1) : 0u, fp, 0u);
      v4f a0 = {0,0,0,0}, a1 = {0,0,0,0}, a2 = {0,0,0,0}, a3 = {0,0,0,0};
      const u16* hb = h0r + (t & (RS - 1)) * (BB * HH) + (long)(g * 16) * HH;
      kh_direct(hb, q, m16, a0, a1, a2, a3);
      float* xpS = xp1 + (long)(t & (RS - 1)) * (GG * BB);
      stg16_f(&xpS[(long)(rbase + 0 * 16 + m16) * BB + bq], a0 + bias[0]);
      stg16_f(&xpS[(long)(rbase + 1 * 16 + m16) * BB + bq], a1 + bias[1]);
      stg16_f(&xpS[(long)(rbase + 2 * 16 + m16) * BB + bq], a2 + bias[2]);
      stg16_f(&xpS[(long)(rbase + 3 * 16 + m16) * BB + bq], a3 + bias[3]);
      drain_stores();
      postw(myf, (u32)(t + 1), lane);
    }
  } else {
    // ===== L1: gates = xp1 + W_hh1 @ h1[t-1]; cell + last-step capture =====
    const int ubase = sid * 16;
    for (int c2 = tid; c2 < 64 * 128; c2 += 256) {
      int r = c2 >> 7, kb = c2 & 127;
      int grow = (r >> 4) * HH + ubase + (r & 15);
      const float* src = Whh1 + (long)grow * HH + kb * 8;
      v8b w;
#pragma unroll
      for (int j = 0; j < 8; ++j) w[j] = (short)f2bf(src[j]);
      *(v8b*)&Wlds[(kb * 64 + r) * 8] = w;
    }
    __syncthreads();
    float cst[4] = {0.f, 0.f, 0.f, 0.f};
    int cap[4];
#pragma unroll
    for (int r = 0; r < 4; ++r) {
      int l = lens[bq + r];
      cap[r] = (l > 0) ? (l - 1) : (TT - 1);
    }
    const u32* fa = fA1 + g * 64 + ((lane & 3) << 4) + (sid >> 2);  // 4 xp1 producers
    const u32* fp = fL1 + g * 64 + lane;                            // 64 h peers
    u32* myf = fL1 + g * 64 + sid;
    for (int t = 0; t < TT; ++t) {
      spin3(fa, (u32)(t + 1), fp, (u32)t, fa, 0u);
      const float* xpS = xp1 + (long)(t & (RS - 1)) * (GG * BB);
      v4f xq0 = ldf16cc(&xpS[(long)(0 * HH + ubase + m16) * BB + bq]);
      v4f xq1 = ldf16cc(&xpS[(long)(1 * HH + ubase + m16) * BB + bq]);
      v4f xq2 = ldf16cc(&xpS[(long)(2 * HH + ubase + m16) * BB + bq]);
      v4f xq3 = ldf16cc(&xpS[(long)(3 * HH + ubase + m16) * BB + bq]);
      v4f a0 = {0,0,0,0}, a1 = {0,0,0,0}, a2 = {0,0,0,0}, a3 = {0,0,0,0};
      const u16* hb = h1r + ((t + RS - 1) & (RS - 1)) * (BB * HH) + (long)(g * 16) * HH;
      kh_direct(hb, q, m16, a0, a1, a2, a3);
      a0 += xq0; a1 += xq1; a2 += xq2; a3 += xq3;
      u16* hw = h1r + (t & (RS - 1)) * (BB * HH);
#pragma unroll
      for (int r = 0; r < 4; ++r) {
        float cn = sigm(a1[r]) * cst[r] + sigm(a0[r]) * ftanh(a2[r]);
        cst[r] = cn;
        float hv = sigm(a3[r]) * ftanh(cn);
        stg2_h(&hw[(bq + r) * HH + ubase + m16], f2bf(hv));
        if (t == cap[r]) stg4_f(&lasth[(long)(bq + r) * HH + ubase + m16], hv);
      }
      drain_stores();
      postw(myf, (u32)(t + 1), lane);
    }
  }
}

// ---------------- final: out = last_h1 @ W_out^T + b_out (all fp32) ----------------
__global__ void out_kernel(const float* __restrict__ lasth, const float* __restrict__ Wout,
                           const float* __restrict__ bout, float* __restrict__ out) {
  int b = blockIdx.x;
  int k = threadIdx.x;
  if (k < 10) {
    float acc = bout[k];
    const float* hb = lasth + (long)b * HH;
    const float* wr = Wout + (long)k * HH;
    for (int j = 0; j < HH; ++j) acc += hb[j] * wr[j];
    out[b * 10 + k] = acc;
  }
}

extern "C" void kernel_launch(void* const* d_in, const int* in_sizes, int n_in,
                              void* d_out, int out_size, void* d_ws, size_t ws_size,
                              hipStream_t stream) {
  const int*   x    = (const int*)d_in[0];
  const float* emb  = (const float*)d_in[1];
  const float* Wih0 = (const float*)d_in[2];
  const float* Whh0 = (const float*)d_in[3];
  const float* b0   = (const float*)d_in[4];
  const float* Wih1 = (const float*)d_in[5];
  const float* Whh1 = (const float*)d_in[6];
  const float* b1   = (const float*)d_in[7];
  const float* Wout = (const float*)d_in[8];
  const float* bout = (const float*)d_in[9];

  char* ws = (char*)d_ws;
  u16*   e16   = (u16*)(ws + 0);            // 33,554,432 B
  float* xp0   = (float*)(ws + 33554432);   // 8 slots * 4096*64*4 = 8,388,608 B
  float* xp1   = (float*)(ws + 41943040);   // 8 slots = 8,388,608 B
  u16*   h0r   = (u16*)(ws + 50331648);     // 8 slots * 64*1024*2 = 1,048,576 B
  u16*   h1r   = (u16*)(ws + 51380224);     // 1,048,576 B
  float* lasth = (float*)(ws + 52428800);   // 262,144 B
  int*   lens  = (int*)(ws + 52690944);     // 256 B
  u32*   flags = (u32*)(ws + 52691200);     // 4 arrays * 4 groups * 64 = 4,096 B
  u32* fA0 = flags;
  u32* fL0 = fA0 + 4 * NSG;
  u32* fA1 = fL0 + 4 * NSG;
  u32* fL1 = fA1 + 4 * NSG;
  int flag_u32s = 16 * NSG;

  (void)hipFuncSetAttribute((const void*)lstm_persist,
                            hipFuncAttributeMaxDynamicSharedMemorySize, 131072);

  prep_kernel<<<2048, 256, 0, stream>>>(x, emb, e16, h0r, h1r, lens, flags, flag_u32s);
  lstm_persist<<<4 * NSG, 256, 131072, stream>>>(e16, Wih0, Whh0, b0, Wih1, Whh1, b1, lens,
                                                 xp0, xp1, h0r, h1r, lasth, fA0, fL0, fA1, fL1);
  out_kernel<<<BB, 64, 0, stream>>>(lasth, Wout, bout, (float*)d_out);
}

// Round 10
// 5556.544 us; speedup vs baseline: 1.1607x; 1.1607x over previous
//
#include <hip/hip_runtime.h>
#include <stdint.h>

#define BB 64
#define TT 512
#define EE 512
#define HH 1024
#define GG 4096

#define NSG 64          // WGs per stage
#define XP0_SLOTS 8
#define RS 8            // h0/h1/xp1 ring slots (depth needed for amortized checks)

typedef short v8b __attribute__((ext_vector_type(8)));
typedef float v4f __attribute__((ext_vector_type(4)));
typedef unsigned short u16;
typedef unsigned int u32;
typedef unsigned long long u64;

__device__ __forceinline__ u16 f2bf(float f) {
  union { float f; u32 i; } v; v.f = f;
  u32 u = v.i;
  return (u16)((u + 0x7FFFu + ((u >> 16) & 1u)) >> 16);
}
__device__ __forceinline__ float sigm(float x) { return 1.0f / (1.0f + __expf(-x)); }
// fast tanh: 1 - 2/(e^{2x}+1); monotone-safe for all x (no inf/inf)
__device__ __forceinline__ float ftanh(float x) {
  float e = __expf(2.0f * x);
  return 1.0f - 2.0f / (e + 1.0f);
}

// ---- MALL-coherent accessors (agent scope, compiler-tracked waitcnts) ----
__device__ __forceinline__ u64 ld8a(const void* p) {
  return __hip_atomic_load((const u64*)p, __ATOMIC_RELAXED, __HIP_MEMORY_SCOPE_AGENT);
}
__device__ __forceinline__ v4f ldf16a(const float* p) {
  union { v4f f; u64 q[2]; } u;
  u.q[0] = ld8a((const u64*)p);
  u.q[1] = ld8a((const u64*)p + 1);
  return u.f;
}
__device__ __forceinline__ void stg16_f(float* p, v4f v) {
  union { v4f f; u64 q[2]; } u; u.f = v;
  __hip_atomic_store((u64*)p,     u.q[0], __ATOMIC_RELAXED, __HIP_MEMORY_SCOPE_AGENT);
  __hip_atomic_store((u64*)p + 1, u.q[1], __ATOMIC_RELAXED, __HIP_MEMORY_SCOPE_AGENT);
}
__device__ __forceinline__ void stg2_h(u16* p, u16 v) {
  __hip_atomic_store(p, v, __ATOMIC_RELAXED, __HIP_MEMORY_SCOPE_AGENT);
}
__device__ __forceinline__ void stg4_f(float* p, float v) {
  __hip_atomic_store(p, v, __ATOMIC_RELAXED, __HIP_MEMORY_SCOPE_AGENT);
}
__device__ __forceinline__ void drain_stores() {
  asm volatile("s_waitcnt vmcnt(0)" ::: "memory");
}

// ---------------- flag helpers: per-(group,WG) monotone counters in MALL ----------------
// R3-style serial && spins; the amortization (below) removes the rarely-binding
// conditions from 3 of every 4 steps, so the common-case spin is ONE flag load.
__device__ __forceinline__ u32 ldflag(const u32* p) {
  return __hip_atomic_load(p, __ATOMIC_RELAXED, __HIP_MEMORY_SCOPE_AGENT);
}
__device__ __forceinline__ void spin1(const u32* p0, u32 v0) {
  for (;;) {
    bool ok = (ldflag(p0) >= v0);
    if (__all((int)ok)) break;
    __builtin_amdgcn_s_sleep(1);
  }
}
__device__ __forceinline__ void spin2(const u32* p0, u32 v0,
                                      const u32* p1, u32 v1) {
  for (;;) {
    bool ok = (ldflag(p0) >= v0) && (ldflag(p1) >= v1);
    if (__all((int)ok)) break;
    __builtin_amdgcn_s_sleep(1);
  }
}
__device__ __forceinline__ void spin3(const u32* p0, u32 v0,
                                      const u32* p1, u32 v1,
                                      const u32* p2, u32 v2) {
  for (;;) {
    bool ok = (ldflag(p0) >= v0) && (ldflag(p1) >= v1) && (ldflag(p2) >= v2);
    if (__all((int)ok)) break;
    __builtin_amdgcn_s_sleep(1);
  }
}
__device__ __forceinline__ void postw(u32* f, u32 v, int lane) {
  if (lane == 0)
    __hip_atomic_store(f, v, __ATOMIC_RELAXED, __HIP_MEMORY_SCOPE_AGENT);
}

// ---------------- prep: gather embeddings (fp32->bf16), zero flags + h rings, lens ----------
__global__ void prep_kernel(const int* __restrict__ x, const float* __restrict__ emb,
                            u16* __restrict__ e16, u16* __restrict__ h0r, u16* __restrict__ h1r,
                            int* __restrict__ lens, u32* flags, int flag_u32s) {
  long stride = (long)gridDim.x * blockDim.x;
  long gid = (long)blockIdx.x * blockDim.x + threadIdx.x;
  const long totalE = (long)BB * TT * EE;
  for (long i = gid; i < totalE; i += stride) {
    int d = (int)(i % EE);
    long bt = i / EE;
    int tok = x[bt];
    e16[i] = f2bf(emb[(long)tok * EE + d]);
  }
  for (long i = gid; i < (long)flag_u32s; i += stride) flags[i] = 0u;
  const long ringN = (long)RS * BB * HH;
  for (long i = gid; i < ringN; i += stride) { h0r[i] = 0; h1r[i] = 0; }
  int gwave = (int)(gid >> 6);
  int lane = (int)(gid & 63);
  if (gwave < BB) {
    int cnt = 0;
    for (int t2 = lane; t2 < TT; t2 += 64) cnt += (x[gwave * TT + t2] == 0) ? 1 : 0;
    for (int off = 32; off; off >>= 1) cnt += __shfl_down(cnt, off, 64);
    if (lane == 0) lens[gwave] = TT - cnt;
  }
}

extern __shared__ short Wlds[];  // 128 KB weights + 16 KB per-wave h staging = 144 KB

// one 32-wide K-block: 4 ds_read_b128 (4 n-tiles of 16 rows) + 4 MFMA
#define KQUAD(FR, PK) \
  { const short* wb = &Wlds[(((PK) * 4 + q) * 64 + m16) * 8]; \
    v8b w0 = *(const v8b*)(wb); \
    v8b w1 = *(const v8b*)(wb + 128); \
    v8b w2 = *(const v8b*)(wb + 256); \
    v8b w3 = *(const v8b*)(wb + 384); \
    a0 = __builtin_amdgcn_mfma_f32_16x16x32_bf16(FR, w0, a0, 0, 0, 0); \
    a1 = __builtin_amdgcn_mfma_f32_16x16x32_bf16(FR, w1, a1, 0, 0, 0); \
    a2 = __builtin_amdgcn_mfma_f32_16x16x32_bf16(FR, w2, a2, 0, 0, 0); \
    a3 = __builtin_amdgcn_mfma_f32_16x16x32_bf16(FR, w3, a3, 0, 0, 0); }

// K=1024 recurrent GEMM for one wave's 16-batch group (R3-verbatim).
// 1) issue ALL 64 sector-exact 8B coherent loads of the 32 KB h-group (held in VGPRs)
// 2) per 64-unit chunk: ds_write (XOR-swizzled) -> ds_read A-frags -> 2x KQUAD
// Double-buffered 2 KB LDS chunks; zero barriers (all wave-local).
__device__ __forceinline__ void kh_staged(const u16* hbase /* slot + group base */,
                                          int lbase /* short idx of wave stage area */,
                                          int lane, int q, int m16,
                                          v4f& a0, v4f& a1, v4f& a2, v4f& a3) {
  const int lrow = lane >> 4;    // 0..3 (row sub-index for loads)
  const int lcol = lane & 15;    // u64 slot within 128B row-chunk
  const int wG = lcol >> 1;      // 16B granule (0..7)
  const int wH = lane & 1;       // 8B half
  u64 hh[64];
#pragma unroll
  for (int c = 0; c < 16; ++c) {
#pragma unroll
    for (int j = 0; j < 4; ++j) {
      const u16* p = hbase + (long)(lrow + 4 * j) * HH + c * 64;
      hh[c * 4 + j] = ld8a((const u64*)p + lcol);
    }
  }
  // stage chunk 0
#pragma unroll
  for (int j = 0; j < 4; ++j) {
    int r = lrow + 4 * j;
    int Gs = wG ^ (r & 7);
    *(u64*)&Wlds[lbase + r * 64 + Gs * 8 + wH * 4] = hh[j];
  }
#pragma unroll
  for (int c = 0; c < 16; ++c) {
    const int boff = lbase + (c & 1) * 1024;
#pragma unroll
    for (int kb = 0; kb < 2; ++kb) {
      int Gs = (q + 4 * kb) ^ (m16 & 7);
      v8b fr = *(const v8b*)&Wlds[boff + m16 * 64 + Gs * 8];
      KQUAD(fr, c * 2 + kb);
    }
    if (c < 15) {
      const int woff = lbase + ((c + 1) & 1) * 1024;
#pragma unroll
      for (int j = 0; j < 4; ++j) {
        int r = lrow + 4 * j;
        int Gs = wG ^ (r & 7);
        *(u64*)&Wlds[woff + r * 64 + Gs * 8 + wH * 4] = hh[(c + 1) * 4 + j];
      }
    }
  }
}

// ---------------- persistent pipeline kernel: 4 stages x 64 WGs, 1 WG/CU ----------------
// Each wave = independent 16-batch pipeline (no __syncthreads in the t-loop).
__global__ __launch_bounds__(256, 1) void lstm_persist(
    const u16* __restrict__ e16,
    const float* __restrict__ Wih0, const float* __restrict__ Whh0, const float* __restrict__ b0,
    const float* __restrict__ Wih1, const float* __restrict__ Whh1, const float* __restrict__ b1,
    const int* __restrict__ lens,
    float* __restrict__ xp0, float* __restrict__ xp1,
    u16* __restrict__ h0r, u16* __restrict__ h1r,
    float* __restrict__ lasth,
    u32* fA0, u32* fL0, u32* fA1, u32* fL1) {
  const int wg = blockIdx.x;
  const int tid = threadIdx.x;
  const int g = tid >> 6;            // wave = batch group (16 batches)
  const int lane = tid & 63;
  const int m16 = lane & 15;
  const int q = lane >> 4;
  const int bq = g * 16 + q * 4;     // C-tile batch base
  const int stage = wg >> 6;
  const int sid = wg & 63;
  const int lbase = 65536 + g * 2048;  // per-wave 4 KB stage area (shorts)

  if (stage == 0) {
    // ===== A0: xp0[t] = W_ih0 @ e_t + b0 (rows sid*64..+63, K=512) =====
    const int rbase = sid * 64;
    for (int c2 = tid; c2 < 64 * 64; c2 += 256) {
      int r = c2 >> 6, kb = c2 & 63;
      const float* src = Wih0 + (long)(rbase + r) * EE + kb * 8;
      v8b w;
#pragma unroll
      for (int j = 0; j < 8; ++j) w[j] = (short)f2bf(src[j]);
      *(v8b*)&Wlds[(kb * 64 + r) * 8] = w;
    }
    __syncthreads();
    float bias[4];
#pragma unroll
    for (int nt = 0; nt < 4; ++nt) bias[nt] = b0[rbase + nt * 16 + m16];
    const u32* cf = fL0 + g * 64 + (sid & 15) * 4 + (lane & 3);  // L0 consumers of our rows
    u32* myf = fA0 + g * 64 + sid;
    for (int t = 0; t < TT; ++t) {
      // amortized overwrite check: every 4th step, consumer >= t-4 covers t..t+3
      if ((t & 3) == 0 && t >= 8) spin1(cf, (u32)(t - 4));
      v4f a0 = {0,0,0,0}, a1 = {0,0,0,0}, a2 = {0,0,0,0}, a3 = {0,0,0,0};
      const u16* ap = e16 + (long)(g * 16 + m16) * (TT * EE) + (long)t * EE + q * 8;
#pragma unroll
      for (int kb = 0; kb < 16; ++kb) {
        v8b fr = *(const v8b*)(ap + kb * 32);  // plain cached load (e16 static)
        KQUAD(fr, kb);
      }
      float* xpS = xp0 + (long)(t & (XP0_SLOTS - 1)) * (GG * BB);
      stg16_f(&xpS[(long)(rbase + 0 * 16 + m16) * BB + bq], a0 + bias[0]);
      stg16_f(&xpS[(long)(rbase + 1 * 16 + m16) * BB + bq], a1 + bias[1]);
      stg16_f(&xpS[(long)(rbase + 2 * 16 + m16) * BB + bq], a2 + bias[2]);
      stg16_f(&xpS[(long)(rbase + 3 * 16 + m16) * BB + bq], a3 + bias[3]);
      drain_stores();
      postw(myf, (u32)(t + 1), lane);
    }
  } else if (stage == 1) {
    // ===== L0: gates = xp0 + W_hh0 @ h0[t-1]; 16 units, lane-local cell =====
    const int ubase = sid * 16;
    for (int c2 = tid; c2 < 64 * 128; c2 += 256) {
      int r = c2 >> 7, kb = c2 & 127;
      int grow = (r >> 4) * HH + ubase + (r & 15);  // rows: [i 0..15 | f | g | o]
      const float* src = Whh0 + (long)grow * HH + kb * 8;
      v8b w;
#pragma unroll
      for (int j = 0; j < 8; ++j) w[j] = (short)f2bf(src[j]);
      *(v8b*)&Wlds[(kb * 64 + r) * 8] = w;
    }
    __syncthreads();
    float cst[4] = {0.f, 0.f, 0.f, 0.f};
    const u32* fa = fA0 + g * 64 + ((lane & 3) << 4) + (sid >> 2);  // 4 xp producers
    const u32* fp = fL0 + g * 64 + lane;                            // 64 h peers
    const u32* fr_ = fA1 + g * 64 + lane;                           // h0 ring consumers
    u32* myf = fL0 + g * 64 + sid;
    for (int t = 0; t < TT; ++t) {
      if ((t & 3) == 0) {
        // boundary: fa >= t+4 covers xp availability for t..t+3;
        // fr_ >= t-4 covers h0-ring overwrites for t..t+3 (RS=8)
        u32 va = (u32)((t + 4 < TT) ? t + 4 : TT);
        u32 vr = (t >= 8) ? (u32)(t - 4) : 0u;
        spin3(fa, va, fp, (u32)t, fr_, vr);
      } else {
        spin1(fp, (u32)t);   // common case: ONE flag load (true recurrence wait)
      }
      const float* xpS = xp0 + (long)(t & (XP0_SLOTS - 1)) * (GG * BB);
      v4f xq0 = ldf16a(&xpS[(long)(0 * HH + ubase + m16) * BB + bq]);
      v4f xq1 = ldf16a(&xpS[(long)(1 * HH + ubase + m16) * BB + bq]);
      v4f xq2 = ldf16a(&xpS[(long)(2 * HH + ubase + m16) * BB + bq]);
      v4f xq3 = ldf16a(&xpS[(long)(3 * HH + ubase + m16) * BB + bq]);
      v4f a0 = {0,0,0,0}, a1 = {0,0,0,0}, a2 = {0,0,0,0}, a3 = {0,0,0,0};
      const u16* hb = h0r + ((t + RS - 1) & (RS - 1)) * (BB * HH) + (long)(g * 16) * HH;
      kh_staged(hb, lbase, lane, q, m16, a0, a1, a2, a3);
      a0 += xq0; a1 += xq1; a2 += xq2; a3 += xq3;   // i, f, g, o
      u16* hw = h0r + (t & (RS - 1)) * (BB * HH);
#pragma unroll
      for (int r = 0; r < 4; ++r) {
        float cn = sigm(a1[r]) * cst[r] + sigm(a0[r]) * ftanh(a2[r]);
        cst[r] = cn;
        float hv = sigm(a3[r]) * ftanh(cn);
        stg2_h(&hw[(bq + r) * HH + ubase + m16], f2bf(hv));
      }
      drain_stores();
      postw(myf, (u32)(t + 1), lane);
    }
  } else if (stage == 2) {
    // ===== A1: xp1[t] = W_ih1 @ h0[t] + b1 (rows sid*64..+63, K=1024) =====
    const int rbase = sid * 64;
    for (int c2 = tid; c2 < 64 * 128; c2 += 256) {
      int r = c2 >> 7, kb = c2 & 127;
      const float* src = Wih1 + (long)(rbase + r) * HH + kb * 8;
      v8b w;
#pragma unroll
      for (int j = 0; j < 8; ++j) w[j] = (short)f2bf(src[j]);
      *(v8b*)&Wlds[(kb * 64 + r) * 8] = w;
    }
    __syncthreads();
    float bias[4];
#pragma unroll
    for (int nt = 0; nt < 4; ++nt) bias[nt] = b1[rbase + nt * 16 + m16];
    const u32* fp = fL0 + g * 64 + lane;                           // h0 producers
    const u32* fc = fL1 + g * 64 + (sid & 15) * 4 + (lane & 3);   // xp1 ring consumers
    u32* myf = fA1 + g * 64 + sid;
    for (int t = 0; t < TT; ++t) {
      if ((t & 3) == 0) {
        u32 vc = (t >= 8) ? (u32)(t - 4) : 0u;   // xp1-ring overwrite, amortized (RS=8)
        spin2(fp, (u32)(t + 1), fc, vc);
      } else {
        spin1(fp, (u32)(t + 1));
      }
      v4f a0 = {0,0,0,0}, a1 = {0,0,0,0}, a2 = {0,0,0,0}, a3 = {0,0,0,0};
      const u16* hb = h0r + (t & (RS - 1)) * (BB * HH) + (long)(g * 16) * HH;
      kh_staged(hb, lbase, lane, q, m16, a0, a1, a2, a3);
      float* xpS = xp1 + (long)(t & (RS - 1)) * (GG * BB);
      stg16_f(&xpS[(long)(rbase + 0 * 16 + m16) * BB + bq], a0 + bias[0]);
      stg16_f(&xpS[(long)(rbase + 1 * 16 + m16) * BB + bq], a1 + bias[1]);
      stg16_f(&xpS[(long)(rbase + 2 * 16 + m16) * BB + bq], a2 + bias[2]);
      stg16_f(&xpS[(long)(rbase + 3 * 16 + m16) * BB + bq], a3 + bias[3]);
      drain_stores();
      postw(myf, (u32)(t + 1), lane);
    }
  } else {
    // ===== L1: gates = xp1 + W_hh1 @ h1[t-1]; cell + last-step capture =====
    const int ubase = sid * 16;
    for (int c2 = tid; c2 < 64 * 128; c2 += 256) {
      int r = c2 >> 7, kb = c2 & 127;
      int grow = (r >> 4) * HH + ubase + (r & 15);
      const float* src = Whh1 + (long)grow * HH + kb * 8;
      v8b w;
#pragma unroll
      for (int j = 0; j < 8; ++j) w[j] = (short)f2bf(src[j]);
      *(v8b*)&Wlds[(kb * 64 + r) * 8] = w;
    }
    __syncthreads();
    float cst[4] = {0.f, 0.f, 0.f, 0.f};
    int cap[4];
#pragma unroll
    for (int r = 0; r < 4; ++r) {
      int l = lens[bq + r];
      cap[r] = (l > 0) ? (l - 1) : (TT - 1);
    }
    const u32* fa = fA1 + g * 64 + ((lane & 3) << 4) + (sid >> 2);  // 4 xp1 producers
    const u32* fp = fL1 + g * 64 + lane;                            // 64 h peers
    u32* myf = fL1 + g * 64 + sid;
    for (int t = 0; t < TT; ++t) {
      spin2(fa, (u32)(t + 1), fp, (u32)t);   // both genuinely bind: R3-exact
      const float* xpS = xp1 + (long)(t & (RS - 1)) * (GG * BB);
      v4f xq0 = ldf16a(&xpS[(long)(0 * HH + ubase + m16) * BB + bq]);
      v4f xq1 = ldf16a(&xpS[(long)(1 * HH + ubase + m16) * BB + bq]);
      v4f xq2 = ldf16a(&xpS[(long)(2 * HH + ubase + m16) * BB + bq]);
      v4f xq3 = ldf16a(&xpS[(long)(3 * HH + ubase + m16) * BB + bq]);
      v4f a0 = {0,0,0,0}, a1 = {0,0,0,0}, a2 = {0,0,0,0}, a3 = {0,0,0,0};
      const u16* hb = h1r + ((t + RS - 1) & (RS - 1)) * (BB * HH) + (long)(g * 16) * HH;
      kh_staged(hb, lbase, lane, q, m16, a0, a1, a2, a3);
      a0 += xq0; a1 += xq1; a2 += xq2; a3 += xq3;
      u16* hw = h1r + (t & (RS - 1)) * (BB * HH);
#pragma unroll
      for (int r = 0; r < 4; ++r) {
        float cn = sigm(a1[r]) * cst[r] + sigm(a0[r]) * ftanh(a2[r]);
        cst[r] = cn;
        float hv = sigm(a3[r]) * ftanh(cn);
        stg2_h(&hw[(bq + r) * HH + ubase + m16], f2bf(hv));
        if (t == cap[r]) stg4_f(&lasth[(long)(bq + r) * HH + ubase + m16], hv);
      }
      drain_stores();
      postw(myf, (u32)(t + 1), lane);
    }
  }
}

// ---------------- final: out = last_h1 @ W_out^T + b_out (all fp32) ----------------
__global__ void out_kernel(const float* __restrict__ lasth, const float* __restrict__ Wout,
                           const float* __restrict__ bout, float* __restrict__ out) {
  int b = blockIdx.x;
  int k = threadIdx.x;
  if (k < 10) {
    float acc = bout[k];
    const float* hb = lasth + (long)b * HH;
    const float* wr = Wout + (long)k * HH;
    for (int j = 0; j < HH; ++j) acc += hb[j] * wr[j];
    out[b * 10 + k] = acc;
  }
}

extern "C" void kernel_launch(void* const* d_in, const int* in_sizes, int n_in,
                              void* d_out, int out_size, void* d_ws, size_t ws_size,
                              hipStream_t stream) {
  const int*   x    = (const int*)d_in[0];
  const float* emb  = (const float*)d_in[1];
  const float* Wih0 = (const float*)d_in[2];
  const float* Whh0 = (const float*)d_in[3];
  const float* b0   = (const float*)d_in[4];
  const float* Wih1 = (const float*)d_in[5];
  const float* Whh1 = (const float*)d_in[6];
  const float* b1   = (const float*)d_in[7];
  const float* Wout = (const float*)d_in[8];
  const float* bout = (const float*)d_in[9];

  char* ws = (char*)d_ws;
  u16*   e16   = (u16*)(ws + 0);            // 33,554,432 B
  float* xp0   = (float*)(ws + 33554432);   // 8 slots * 4096*64*4 = 8,388,608 B
  float* xp1   = (float*)(ws + 41943040);   // 8 slots = 8,388,608 B
  u16*   h0r   = (u16*)(ws + 50331648);     // 8 slots * 64*1024*2 = 1,048,576 B
  u16*   h1r   = (u16*)(ws + 51380224);     // 1,048,576 B
  float* lasth = (float*)(ws + 52428800);   // 262,144 B
  int*   lens  = (int*)(ws + 52690944);     // 256 B
  u32*   flags = (u32*)(ws + 52691200);     // 4 arrays * 4 groups * 64 = 4,096 B
  u32* fA0 = flags;
  u32* fL0 = fA0 + 4 * NSG;
  u32* fA1 = fL0 + 4 * NSG;
  u32* fL1 = fA1 + 4 * NSG;
  int flag_u32s = 16 * NSG;

  (void)hipFuncSetAttribute((const void*)lstm_persist,
                            hipFuncAttributeMaxDynamicSharedMemorySize, 147456);

  prep_kernel<<<2048, 256, 0, stream>>>(x, emb, e16, h0r, h1r, lens, flags, flag_u32s);
  lstm_persist<<<4 * NSG, 256, 147456, stream>>>(e16, Wih0, Whh0, b0, Wih1, Whh1, b1, lens,
                                                 xp0, xp1, h0r, h1r, lasth, fA0, fL0, fA1, fL1);
  out_kernel<<<BB, 64, 0, stream>>>(lasth, Wout, bout, (float*)d_out);
}

// Round 11
// 5158.761 us; speedup vs baseline: 1.2502x; 1.0771x over previous
//
#include <hip/hip_runtime.h>
#include <stdint.h>

#define BB 64
#define TT 512
#define EE 512
#define HH 1024
#define GG 4096

#define NSG 64          // WGs per stage
#define XP0_SLOTS 8

typedef short v8b __attribute__((ext_vector_type(8)));
typedef float v4f __attribute__((ext_vector_type(4)));
typedef unsigned short u16;
typedef unsigned int u32;
typedef unsigned long long u64;

__device__ __forceinline__ u16 f2bf(float f) {
  union { float f; u32 i; } v; v.f = f;
  u32 u = v.i;
  return (u16)((u + 0x7FFFu + ((u >> 16) & 1u)) >> 16);
}
__device__ __forceinline__ float sigm(float x) { return 1.0f / (1.0f + __expf(-x)); }
// fast tanh: 1 - 2/(e^{2x}+1); monotone-safe for all x (no inf/inf)
__device__ __forceinline__ float ftanh(float x) {
  float e = __expf(2.0f * x);
  return 1.0f - 2.0f / (e + 1.0f);
}

// ---- MALL-coherent accessors (agent scope, compiler-tracked waitcnts) ----
__device__ __forceinline__ u64 ld8a(const void* p) {
  return __hip_atomic_load((const u64*)p, __ATOMIC_RELAXED, __HIP_MEMORY_SCOPE_AGENT);
}
__device__ __forceinline__ v4f ldf16a(const float* p) {
  union { v4f f; u64 q[2]; } u;
  u.q[0] = ld8a((const u64*)p);
  u.q[1] = ld8a((const u64*)p + 1);
  return u.f;
}
__device__ __forceinline__ void stg16_f(float* p, v4f v) {
  union { v4f f; u64 q[2]; } u; u.f = v;
  __hip_atomic_store((u64*)p,     u.q[0], __ATOMIC_RELAXED, __HIP_MEMORY_SCOPE_AGENT);
  __hip_atomic_store((u64*)p + 1, u.q[1], __ATOMIC_RELAXED, __HIP_MEMORY_SCOPE_AGENT);
}
__device__ __forceinline__ void stg2_h(u16* p, u16 v) {
  __hip_atomic_store(p, v, __ATOMIC_RELAXED, __HIP_MEMORY_SCOPE_AGENT);
}
__device__ __forceinline__ void stg4_f(float* p, float v) {
  __hip_atomic_store(p, v, __ATOMIC_RELAXED, __HIP_MEMORY_SCOPE_AGENT);
}
__device__ __forceinline__ void drain_stores() {
  asm volatile("s_waitcnt vmcnt(0)" ::: "memory");
}

// ---------------- flag helpers: per-(group,WG) monotone counters in MALL ----------------
__device__ __forceinline__ u32 ldflag(const u32* p) {
  return __hip_atomic_load(p, __ATOMIC_RELAXED, __HIP_MEMORY_SCOPE_AGENT);
}
// per-WAVE spin: each lane checks up to 3 conditions; wave proceeds when all lanes pass
__device__ __forceinline__ void spin3(const u32* p0, u32 v0,
                                      const u32* p1, u32 v1,
                                      const u32* p2, u32 v2) {
  for (;;) {
    bool ok = (ldflag(p0) >= v0) && (ldflag(p1) >= v1) && (ldflag(p2) >= v2);
    if (__all((int)ok)) break;
    __builtin_amdgcn_s_sleep(1);
  }
}
__device__ __forceinline__ void postw(u32* f, u32 v, int lane) {
  if (lane == 0)
    __hip_atomic_store(f, v, __ATOMIC_RELAXED, __HIP_MEMORY_SCOPE_AGENT);
}

// ---------------- prep: gather embeddings (fp32->bf16), zero flags + h rings, lens ----------
__global__ void prep_kernel(const int* __restrict__ x, const float* __restrict__ emb,
                            u16* __restrict__ e16, u16* __restrict__ h0r, u16* __restrict__ h1r,
                            int* __restrict__ lens, u32* flags, int flag_u32s) {
  long stride = (long)gridDim.x * blockDim.x;
  long gid = (long)blockIdx.x * blockDim.x + threadIdx.x;
  const long totalE = (long)BB * TT * EE;
  for (long i = gid; i < totalE; i += stride) {
    int d = (int)(i % EE);
    long bt = i / EE;
    int tok = x[bt];
    e16[i] = f2bf(emb[(long)tok * EE + d]);
  }
  for (long i = gid; i < (long)flag_u32s; i += stride) flags[i] = 0u;
  const long ringN = 4L * BB * HH;
  for (long i = gid; i < ringN; i += stride) { h0r[i] = 0; h1r[i] = 0; }
  int gwave = (int)(gid >> 6);
  int lane = (int)(gid & 63);
  if (gwave < BB) {
    int cnt = 0;
    for (int t2 = lane; t2 < TT; t2 += 64) cnt += (x[gwave * TT + t2] == 0) ? 1 : 0;
    for (int off = 32; off; off >>= 1) cnt += __shfl_down(cnt, off, 64);
    if (lane == 0) lens[gwave] = TT - cnt;
  }
}

extern __shared__ short Wlds[];  // dynamic: 128 KB weights + 16 KB per-wave h stage = 144 KB

// one 32-wide K-block: 4 ds_read_b128 (4 n-tiles of 16 rows) + 4 MFMA
#define KQUAD(FR, PK) \
  { const short* wb = &Wlds[(((PK) * 4 + q) * 64 + m16) * 8]; \
    v8b w0 = *(const v8b*)(wb); \
    v8b w1 = *(const v8b*)(wb + 128); \
    v8b w2 = *(const v8b*)(wb + 256); \
    v8b w3 = *(const v8b*)(wb + 384); \
    a0 = __builtin_amdgcn_mfma_f32_16x16x32_bf16(FR, w0, a0, 0, 0, 0); \
    a1 = __builtin_amdgcn_mfma_f32_16x16x32_bf16(FR, w1, a1, 0, 0, 0); \
    a2 = __builtin_amdgcn_mfma_f32_16x16x32_bf16(FR, w2, a2, 0, 0, 0); \
    a3 = __builtin_amdgcn_mfma_f32_16x16x32_bf16(FR, w3, a3, 0, 0, 0); }

// K=1024 recurrent GEMM for one wave's 16-batch group.
// 1) issue ALL 64 sector-exact 8B coherent loads of the 32 KB h-group (held in VGPRs)
// 2) per 64-unit chunk: ds_write (XOR-swizzled) -> ds_read A-frags -> 2x KQUAD
// Double-buffered 2 KB LDS chunks; zero barriers (all wave-local).
__device__ __forceinline__ void kh_staged(const u16* hbase /* slot + group base */,
                                          int lbase /* short idx of wave stage area */,
                                          int lane, int q, int m16,
                                          v4f& a0, v4f& a1, v4f& a2, v4f& a3) {
  const int lrow = lane >> 4;    // 0..3 (row sub-index for loads)
  const int lcol = lane & 15;    // u64 slot within 128B row-chunk
  const int wG = lcol >> 1;      // 16B granule (0..7)
  const int wH = lane & 1;       // 8B half
  u64 hh[64];
#pragma unroll
  for (int c = 0; c < 16; ++c) {
#pragma unroll
    for (int j = 0; j < 4; ++j) {
      const u16* p = hbase + (long)(lrow + 4 * j) * HH + c * 64;
      hh[c * 4 + j] = ld8a((const u64*)p + lcol);
    }
  }
  // stage chunk 0
#pragma unroll
  for (int j = 0; j < 4; ++j) {
    int r = lrow + 4 * j;
    int Gs = wG ^ (r & 7);
    *(u64*)&Wlds[lbase + r * 64 + Gs * 8 + wH * 4] = hh[j];
  }
#pragma unroll
  for (int c = 0; c < 16; ++c) {
    const int boff = lbase + (c & 1) * 1024;
#pragma unroll
    for (int kb = 0; kb < 2; ++kb) {
      int Gs = (q + 4 * kb) ^ (m16 & 7);
      v8b fr = *(const v8b*)&Wlds[boff + m16 * 64 + Gs * 8];
      KQUAD(fr, c * 2 + kb);
    }
    if (c < 15) {
      const int woff = lbase + ((c + 1) & 1) * 1024;
#pragma unroll
      for (int j = 0; j < 4; ++j) {
        int r = lrow + 4 * j;
        int Gs = wG ^ (r & 7);
        *(u64*)&Wlds[woff + r * 64 + Gs * 8 + wH * 4] = hh[(c + 1) * 4 + j];
      }
    }
  }
}

// ---------------- persistent pipeline kernel: 4 stages x 64 WGs, 1 WG/CU ----------------
// Each wave = independent 16-batch pipeline (no __syncthreads in the t-loop).
__global__ __launch_bounds__(256, 1) void lstm_persist(
    const u16* __restrict__ e16,
    const float* __restrict__ Wih0, const float* __restrict__ Whh0, const float* __restrict__ b0,
    const float* __restrict__ Wih1, const float* __restrict__ Whh1, const float* __restrict__ b1,
    const int* __restrict__ lens,
    float* __restrict__ xp0, float* __restrict__ xp1,
    u16* __restrict__ h0r, u16* __restrict__ h1r,
    float* __restrict__ lasth,
    u32* fA0, u32* fL0, u32* fA1, u32* fL1) {
  const int wg = blockIdx.x;
  const int tid = threadIdx.x;
  const int g = tid >> 6;            // wave = batch group (16 batches)
  const int lane = tid & 63;
  const int m16 = lane & 15;
  const int q = lane >> 4;
  const int bq = g * 16 + q * 4;     // C-tile batch base
  const int stage = wg >> 6;
  const int sid = wg & 63;
  const int lbase = 65536 + g * 2048;  // per-wave 4 KB stage area (shorts)

  if (stage == 0) {
    // ===== A0: xp0[t] = W_ih0 @ e_t + b0 (rows sid*64..+63, K=512) =====
    const int rbase = sid * 64;
    for (int c2 = tid; c2 < 64 * 64; c2 += 256) {
      int r = c2 >> 6, kb = c2 & 63;
      const float* src = Wih0 + (long)(rbase + r) * EE + kb * 8;
      v8b w;
#pragma unroll
      for (int j = 0; j < 8; ++j) w[j] = (short)f2bf(src[j]);
      *(v8b*)&Wlds[(kb * 64 + r) * 8] = w;
    }
    __syncthreads();
    float bias[4];
#pragma unroll
    for (int nt = 0; nt < 4; ++nt) bias[nt] = b0[rbase + nt * 16 + m16];
    const u32* cf = fL0 + g * 64 + (sid & 15) * 4 + (lane & 3);  // L0 consumers of our rows
    u32* myf = fA0 + g * 64 + sid;
    for (int t = 0; t < TT; ++t) {
      if (t >= XP0_SLOTS) spin3(cf, (u32)(t - XP0_SLOTS + 1), cf, 0u, cf, 0u);
      v4f a0 = {0,0,0,0}, a1 = {0,0,0,0}, a2 = {0,0,0,0}, a3 = {0,0,0,0};
      const u16* ap = e16 + (long)(g * 16 + m16) * (TT * EE) + (long)t * EE + q * 8;
#pragma unroll
      for (int kb = 0; kb < 16; ++kb) {
        v8b fr = *(const v8b*)(ap + kb * 32);  // plain cached load (e16 static)
        KQUAD(fr, kb);
      }
      float* xpS = xp0 + (long)(t & (XP0_SLOTS - 1)) * (GG * BB);
      stg16_f(&xpS[(long)(rbase + 0 * 16 + m16) * BB + bq], a0 + bias[0]);
      stg16_f(&xpS[(long)(rbase + 1 * 16 + m16) * BB + bq], a1 + bias[1]);
      stg16_f(&xpS[(long)(rbase + 2 * 16 + m16) * BB + bq], a2 + bias[2]);
      stg16_f(&xpS[(long)(rbase + 3 * 16 + m16) * BB + bq], a3 + bias[3]);
      drain_stores();
      postw(myf, (u32)(t + 1), lane);
    }
  } else if (stage == 1) {
    // ===== L0: gates = xp0 + W_hh0 @ h0[t-1]; 16 units, lane-local cell =====
    const int ubase = sid * 16;
    for (int c2 = tid; c2 < 64 * 128; c2 += 256) {
      int r = c2 >> 7, kb = c2 & 127;
      int grow = (r >> 4) * HH + ubase + (r & 15);  // rows: [i 0..15 | f | g | o]
      const float* src = Whh0 + (long)grow * HH + kb * 8;
      v8b w;
#pragma unroll
      for (int j = 0; j < 8; ++j) w[j] = (short)f2bf(src[j]);
      *(v8b*)&Wlds[(kb * 64 + r) * 8] = w;
    }
    __syncthreads();
    float cst[4] = {0.f, 0.f, 0.f, 0.f};
    const u32* fa = fA0 + g * 64 + ((lane & 3) << 4) + (sid >> 2);  // 4 xp producers
    const u32* fp = fL0 + g * 64 + lane;                            // 64 h peers
    const u32* fr_ = fA1 + g * 64 + lane;                           // h0 ring consumers
    u32* myf = fL0 + g * 64 + sid;
    for (int t = 0; t < TT; ++t) {
      spin3(fa, (u32)(t + 1), fp, (u32)t, fr_, (t >= 4) ? (u32)(t - 3) : 0u);
      const float* xpS = xp0 + (long)(t & (XP0_SLOTS - 1)) * (GG * BB);
      v4f xq0 = ldf16a(&xpS[(long)(0 * HH + ubase + m16) * BB + bq]);
      v4f xq1 = ldf16a(&xpS[(long)(1 * HH + ubase + m16) * BB + bq]);
      v4f xq2 = ldf16a(&xpS[(long)(2 * HH + ubase + m16) * BB + bq]);
      v4f xq3 = ldf16a(&xpS[(long)(3 * HH + ubase + m16) * BB + bq]);
      v4f a0 = {0,0,0,0}, a1 = {0,0,0,0}, a2 = {0,0,0,0}, a3 = {0,0,0,0};
      const u16* hb = h0r + ((t + 3) & 3) * (BB * HH) + (long)(g * 16) * HH;
      kh_staged(hb, lbase, lane, q, m16, a0, a1, a2, a3);
      a0 += xq0; a1 += xq1; a2 += xq2; a3 += xq3;   // i, f, g, o
      u16* hw = h0r + (t & 3) * (BB * HH);
#pragma unroll
      for (int r = 0; r < 4; ++r) {
        float cn = sigm(a1[r]) * cst[r] + sigm(a0[r]) * ftanh(a2[r]);
        cst[r] = cn;
        float hv = sigm(a3[r]) * ftanh(cn);
        stg2_h(&hw[(bq + r) * HH + ubase + m16], f2bf(hv));
      }
      drain_stores();
      postw(myf, (u32)(t + 1), lane);
    }
  } else if (stage == 2) {
    // ===== A1: xp1[t] = W_ih1 @ h0[t] + b1 (rows sid*64..+63, K=1024) =====
    const int rbase = sid * 64;
    for (int c2 = tid; c2 < 64 * 128; c2 += 256) {
      int r = c2 >> 7, kb = c2 & 127;
      const float* src = Wih1 + (long)(rbase + r) * HH + kb * 8;
      v8b w;
#pragma unroll
      for (int j = 0; j < 8; ++j) w[j] = (short)f2bf(src[j]);
      *(v8b*)&Wlds[(kb * 64 + r) * 8] = w;
    }
    __syncthreads();
    float bias[4];
#pragma unroll
    for (int nt = 0; nt < 4; ++nt) bias[nt] = b1[rbase + nt * 16 + m16];
    const u32* fp = fL0 + g * 64 + lane;                           // h0 producers
    const u32* fc = fL1 + g * 64 + (sid & 15) * 4 + (lane & 3);   // xp1 ring consumers
    u32* myf = fA1 + g * 64 + sid;
    for (int t = 0; t < TT; ++t) {
      spin3(fp, (u32)(t + 1), fc, (t >= 4) ? (u32)(t - 3) : 0u, fp, 0u);
      v4f a0 = {0,0,0,0}, a1 = {0,0,0,0}, a2 = {0,0,0,0}, a3 = {0,0,0,0};
      const u16* hb = h0r + (t & 3) * (BB * HH) + (long)(g * 16) * HH;
      kh_staged(hb, lbase, lane, q, m16, a0, a1, a2, a3);
      float* xpS = xp1 + (long)(t & 3) * (GG * BB);
      stg16_f(&xpS[(long)(rbase + 0 * 16 + m16) * BB + bq], a0 + bias[0]);
      stg16_f(&xpS[(long)(rbase + 1 * 16 + m16) * BB + bq], a1 + bias[1]);
      stg16_f(&xpS[(long)(rbase + 2 * 16 + m16) * BB + bq], a2 + bias[2]);
      stg16_f(&xpS[(long)(rbase + 3 * 16 + m16) * BB + bq], a3 + bias[3]);
      drain_stores();
      postw(myf, (u32)(t + 1), lane);
    }
  } else {
    // ===== L1: gates = xp1 + W_hh1 @ h1[t-1]; cell + last-step capture =====
    const int ubase = sid * 16;
    for (int c2 = tid; c2 < 64 * 128; c2 += 256) {
      int r = c2 >> 7, kb = c2 & 127;
      int grow = (r >> 4) * HH + ubase + (r & 15);
      const float* src = Whh1 + (long)grow * HH + kb * 8;
      v8b w;
#pragma unroll
      for (int j = 0; j < 8; ++j) w[j] = (short)f2bf(src[j]);
      *(v8b*)&Wlds[(kb * 64 + r) * 8] = w;
    }
    __syncthreads();
    float cst[4] = {0.f, 0.f, 0.f, 0.f};
    int cap[4];
#pragma unroll
    for (int r = 0; r < 4; ++r) {
      int l = lens[bq + r];
      cap[r] = (l > 0) ? (l - 1) : (TT - 1);
    }
    const u32* fa = fA1 + g * 64 + ((lane & 3) << 4) + (sid >> 2);  // 4 xp1 producers
    const u32* fp = fL1 + g * 64 + lane;                            // 64 h peers
    u32* myf = fL1 + g * 64 + sid;
    for (int t = 0; t < TT; ++t) {
      spin3(fa, (u32)(t + 1), fp, (u32)t, fa, 0u);
      const float* xpS = xp1 + (long)(t & 3) * (GG * BB);
      v4f xq0 = ldf16a(&xpS[(long)(0 * HH + ubase + m16) * BB + bq]);
      v4f xq1 = ldf16a(&xpS[(long)(1 * HH + ubase + m16) * BB + bq]);
      v4f xq2 = ldf16a(&xpS[(long)(2 * HH + ubase + m16) * BB + bq]);
      v4f xq3 = ldf16a(&xpS[(long)(3 * HH + ubase + m16) * BB + bq]);
      v4f a0 = {0,0,0,0}, a1 = {0,0,0,0}, a2 = {0,0,0,0}, a3 = {0,0,0,0};
      const u16* hb = h1r + ((t + 3) & 3) * (BB * HH) + (long)(g * 16) * HH;
      kh_staged(hb, lbase, lane, q, m16, a0, a1, a2, a3);
      a0 += xq0; a1 += xq1; a2 += xq2; a3 += xq3;
      u16* hw = h1r + (t & 3) * (BB * HH);
#pragma unroll
      for (int r = 0; r < 4; ++r) {
        float cn = sigm(a1[r]) * cst[r] + sigm(a0[r]) * ftanh(a2[r]);
        cst[r] = cn;
        float hv = sigm(a3[r]) * ftanh(cn);
        stg2_h(&hw[(bq + r) * HH + ubase + m16], f2bf(hv));
        if (t == cap[r]) stg4_f(&lasth[(long)(bq + r) * HH + ubase + m16], hv);
      }
      drain_stores();
      postw(myf, (u32)(t + 1), lane);
    }
  }
}

// ---------------- final: out = last_h1 @ W_out^T + b_out (all fp32) ----------------
__global__ void out_kernel(const float* __restrict__ lasth, const float* __restrict__ Wout,
                           const float* __restrict__ bout, float* __restrict__ out) {
  int b = blockIdx.x;
  int k = threadIdx.x;
  if (k < 10) {
    float acc = bout[k];
    const float* hb = lasth + (long)b * HH;
    const float* wr = Wout + (long)k * HH;
    for (int j = 0; j < HH; ++j) acc += hb[j] * wr[j];
    out[b * 10 + k] = acc;
  }
}

extern "C" void kernel_launch(void* const* d_in, const int* in_sizes, int n_in,
                              void* d_out, int out_size, void* d_ws, size_t ws_size,
                              hipStream_t stream) {
  const int*   x    = (const int*)d_in[0];
  const float* emb  = (const float*)d_in[1];
  const float* Wih0 = (const float*)d_in[2];
  const float* Whh0 = (const float*)d_in[3];
  const float* b0   = (const float*)d_in[4];
  const float* Wih1 = (const float*)d_in[5];
  const float* Whh1 = (const float*)d_in[6];
  const float* b1   = (const float*)d_in[7];
  const float* Wout = (const float*)d_in[8];
  const float* bout = (const float*)d_in[9];

  char* ws = (char*)d_ws;
  u16*   e16   = (u16*)(ws + 0);            // 33,554,432 B
  float* xp0   = (float*)(ws + 33554432);   // 8 slots * 4096*64*4 = 8,388,608 B
  float* xp1   = (float*)(ws + 41943040);   // 4 slots = 4,194,304 B
  u16*   h0r   = (u16*)(ws + 46137344);     // 524,288 B
  u16*   h1r   = (u16*)(ws + 46661632);     // 524,288 B
  float* lasth = (float*)(ws + 47185920);   // 262,144 B
  int*   lens  = (int*)(ws + 47448064);     // 256 B
  u32*   flags = (u32*)(ws + 47448320);     // 4 arrays * 4 groups * 64 = 4,096 B
  u32* fA0 = flags;
  u32* fL0 = fA0 + 4 * NSG;
  u32* fA1 = fL0 + 4 * NSG;
  u32* fL1 = fA1 + 4 * NSG;
  int flag_u32s = 16 * NSG;

  (void)hipFuncSetAttribute((const void*)lstm_persist,
                            hipFuncAttributeMaxDynamicSharedMemorySize, 147456);

  prep_kernel<<<2048, 256, 0, stream>>>(x, emb, e16, h0r, h1r, lens, flags, flag_u32s);
  lstm_persist<<<4 * NSG, 256, 147456, stream>>>(e16, Wih0, Whh0, b0, Wih1, Whh1, b1, lens,
                                                 xp0, xp1, h0r, h1r, lasth, fA0, fL0, fA1, fL1);
  out_kernel<<<BB, 64, 0, stream>>>(lasth, Wout, bout, (float*)d_out);
}